// Round 1
// baseline (434.961 us; speedup 1.0000x reference)
//
#include <hip/hip_runtime.h>
#include <hip/hip_bf16.h>

typedef __attribute__((ext_vector_type(8))) __bf16 bf16x8;
typedef __attribute__((ext_vector_type(4))) float f32x4;

#define DEVI static __device__ __forceinline__

// ---- helpers ---------------------------------------------------------------

DEVI ushort f2bf(float f) {
  unsigned u = __builtin_bit_cast(unsigned, f);
  return (ushort)((u + 0x7fffu + ((u >> 16) & 1u)) >> 16);
}

union BF8 { unsigned u[4]; bf16x8 v; };

// 8 consecutive f32 -> 8 bf16 (RNE) via packed converts
DEVI bf16x8 cvt8(const float* __restrict__ p) {
  const f32x4 a = *(const f32x4*)p;
  const f32x4 b = *(const f32x4*)(p + 4);
  BF8 r;
  asm("v_cvt_pk_bf16_f32 %0, %1, %2" : "=v"(r.u[0]) : "v"(a.x), "v"(a.y));
  asm("v_cvt_pk_bf16_f32 %0, %1, %2" : "=v"(r.u[1]) : "v"(a.z), "v"(a.w));
  asm("v_cvt_pk_bf16_f32 %0, %1, %2" : "=v"(r.u[2]) : "v"(b.x), "v"(b.y));
  asm("v_cvt_pk_bf16_f32 %0, %1, %2" : "=v"(r.u[3]) : "v"(b.z), "v"(b.w));
  return r.v;
}

// ---- GEMM: C[M,N] = A[M,K] @ W[N,K]^T + bias -------------------------------
// 128x128 tile, BK=32, 256 threads (4 waves, 2x2 of 64x64), mfma 16x16x32 bf16
// A_BF16: A operand already bf16 (ushort*), else f32 converted on the fly.
// OUT_BF16: write bf16 (ushort*) else f32.

template <int A_BF16, int OUT_BF16>
__global__ __launch_bounds__(256) void gemm_kernel(
    const void* __restrict__ Ap, const float* __restrict__ Wp,
    const float* __restrict__ bias, void* __restrict__ Cp, int N, int K) {
  __shared__ ushort As[128 * 32];
  __shared__ ushort Bs[128 * 32];
  const int tid = threadIdx.x;
  const int lane = tid & 63;
  const int wv = tid >> 6;
  const int wr = wv >> 1, wc = wv & 1;
  const int cc = lane & 15, cr = lane >> 4;
  const int ntiles = N >> 7;
  const size_t m0 = (size_t)(blockIdx.x / ntiles) * 128;
  const size_t n0 = (size_t)(blockIdx.x % ntiles) * 128;

  f32x4 acc[4][4] = {};

  for (int kt = 0; kt < K; kt += 32) {
#pragma unroll
    for (int i = 0; i < 2; ++i) {
      const int ch = tid + i * 256;           // 512 chunks of 8 elems
      const int row = ch >> 2, kc = ch & 3;
      bf16x8 va, vb;
      if constexpr (A_BF16) {
        va = *(const bf16x8*)((const ushort*)Ap + (m0 + row) * K + kt + kc * 8);
      } else {
        va = cvt8((const float*)Ap + (m0 + row) * K + kt + kc * 8);
      }
      vb = cvt8(Wp + (n0 + row) * K + kt + kc * 8);
      *(bf16x8*)&As[ch * 8] = va;
      *(bf16x8*)&Bs[ch * 8] = vb;
    }
    __syncthreads();
    bf16x8 af[4], bf[4];
#pragma unroll
    for (int m = 0; m < 4; ++m)
      af[m] = *(const bf16x8*)&As[(wr * 64 + m * 16 + cc) * 32 + cr * 8];
#pragma unroll
    for (int n = 0; n < 4; ++n)
      bf[n] = *(const bf16x8*)&Bs[(wc * 64 + n * 16 + cc) * 32 + cr * 8];
#pragma unroll
    for (int m = 0; m < 4; ++m)
#pragma unroll
      for (int n = 0; n < 4; ++n)
        acc[m][n] =
            __builtin_amdgcn_mfma_f32_16x16x32_bf16(af[m], bf[n], acc[m][n], 0, 0, 0);
    __syncthreads();
  }

#pragma unroll
  for (int n = 0; n < 4; ++n) {
    const size_t col = n0 + wc * 64 + n * 16 + cc;
    const float bval = bias[col];
#pragma unroll
    for (int m = 0; m < 4; ++m) {
      const size_t row0 = m0 + wr * 64 + m * 16 + cr * 4;
#pragma unroll
      for (int r = 0; r < 4; ++r) {
        const float v = acc[m][n][r] + bval;
        if constexpr (OUT_BF16)
          ((ushort*)Cp)[(row0 + r) * N + col] = f2bf(v);
        else
          ((float*)Cp)[(row0 + r) * N + col] = v;
      }
    }
  }
}

// ---- windowed attention ----------------------------------------------------
// grid = B*H*NW = 1024 blocks, 256 threads (4 waves x 64 q-rows).
// q/k/v: bf16 [B*S, D] with col = h*64+dk. x: same layout (bf16 out).

__global__ __launch_bounds__(256) void attn_kernel(
    const ushort* __restrict__ q, const ushort* __restrict__ k,
    const ushort* __restrict__ v, ushort* __restrict__ x) {
  __shared__ ushort Ks[256 * 72];       // K tile, padded stride 72
  __shared__ ushort Vt[64 * 264];       // V transposed [dk][s], padded stride 264
  __shared__ ushort Pw[4][16 * 264];    // per-wave P chunk [16 q-rows][256 cols]
  const int bid = blockIdx.x;
  const int w = bid & 15, h = (bid >> 4) & 15, b = bid >> 8;
  const int tid = threadIdx.x, lane = tid & 63, wv = tid >> 6;
  const int cc = lane & 15, cr = lane >> 4;
  const size_t base = ((size_t)b * 4096 + (size_t)w * 256) * 1024 + h * 64;

  // stage K: [256 rows][64 cols] -> Ks[row*72 + c]
#pragma unroll
  for (int i = 0; i < 8; ++i) {
    const int ch = i * 256 + tid;          // 2048 chunks of 8
    const int row = ch >> 3, kc = ch & 7;
    bf16x8 val = *(const bf16x8*)(k + base + (size_t)row * 1024 + kc * 8);
    *(bf16x8*)&Ks[row * 72 + kc * 8] = val;
  }
  // stage V transposed: Vt[dk*264 + s]
  {
    const ushort* vp = v + base + (size_t)tid * 1024;
#pragma unroll
    for (int j = 0; j < 8; ++j) {
      bf16x8 vv = *(const bf16x8*)(vp + j * 8);
#pragma unroll
      for (int e = 0; e < 8; ++e)
        Vt[(j * 8 + e) * 264 + tid] = __builtin_bit_cast(ushort, (__bf16)vv[e]);
    }
  }
  __syncthreads();

  ushort* Pp = Pw[wv];
  for (int c = 0; c < 4; ++c) {
    const int qrow0 = wv * 64 + c * 16;
    // Q fragments straight from global (each element read once)
    const ushort* qp = q + base + (size_t)(qrow0 + cc) * 1024 + cr * 8;
    const bf16x8 qf0 = *(const bf16x8*)qp;
    const bf16x8 qf1 = *(const bf16x8*)(qp + 32);

    // scores: 16 col-blocks of 16, K-dim 64 = 2 mfma each
    f32x4 sc[16];
#pragma unroll
    for (int cb = 0; cb < 16; ++cb) {
      const bf16x8 b0 = *(const bf16x8*)&Ks[(cb * 16 + cc) * 72 + cr * 8];
      const bf16x8 b1 = *(const bf16x8*)&Ks[(cb * 16 + cc) * 72 + 32 + cr * 8];
      f32x4 z = {0.f, 0.f, 0.f, 0.f};
      z = __builtin_amdgcn_mfma_f32_16x16x32_bf16(qf0, b0, z, 0, 0, 0);
      z = __builtin_amdgcn_mfma_f32_16x16x32_bf16(qf1, b1, z, 0, 0, 0);
      sc[cb] = z;
    }

    // softmax over 256 cols; lane holds rows cr*4+r, cols cb*16+cc
    float inv[4];
#pragma unroll
    for (int r = 0; r < 4; ++r) {
      float mx = -1e30f;
#pragma unroll
      for (int cb = 0; cb < 16; ++cb) mx = fmaxf(mx, sc[cb][r]);
      mx = fmaxf(mx, __shfl_xor(mx, 1));
      mx = fmaxf(mx, __shfl_xor(mx, 2));
      mx = fmaxf(mx, __shfl_xor(mx, 4));
      mx = fmaxf(mx, __shfl_xor(mx, 8));
      float sum = 0.f;
#pragma unroll
      for (int cb = 0; cb < 16; ++cb) {
        const float p = __expf((sc[cb][r] - mx) * 0.125f);
        sc[cb][r] = p;   // unnormalized
        sum += p;
      }
      sum += __shfl_xor(sum, 1);
      sum += __shfl_xor(sum, 2);
      sum += __shfl_xor(sum, 4);
      sum += __shfl_xor(sum, 8);
      inv[r] = 1.f / sum;
    }

    // P (unnormalized) -> LDS bf16
#pragma unroll
    for (int r = 0; r < 4; ++r)
#pragma unroll
      for (int cb = 0; cb < 16; ++cb)
        Pp[(cr * 4 + r) * 264 + cb * 16 + cc] = f2bf(sc[cb][r]);

    // PV: out[16 x 64] = P[16 x 256] @ V[256 x 64]
    bf16x8 pf[8];
#pragma unroll
    for (int ks = 0; ks < 8; ++ks)
      pf[ks] = *(const bf16x8*)&Pp[cc * 264 + ks * 32 + cr * 8];
    f32x4 o[4] = {};
#pragma unroll
    for (int db = 0; db < 4; ++db)
#pragma unroll
      for (int ks = 0; ks < 8; ++ks) {
        const bf16x8 bv = *(const bf16x8*)&Vt[(db * 16 + cc) * 264 + ks * 32 + cr * 8];
        o[db] = __builtin_amdgcn_mfma_f32_16x16x32_bf16(pf[ks], bv, o[db], 0, 0, 0);
      }

    // normalize by 1/rowsum and store
#pragma unroll
    for (int db = 0; db < 4; ++db)
#pragma unroll
      for (int r = 0; r < 4; ++r) {
        const int qr = qrow0 + cr * 4 + r;
        x[base + (size_t)qr * 1024 + db * 16 + cc] = f2bf(o[db][r] * inv[r]);
      }
  }
}

// ---- launch ----------------------------------------------------------------

extern "C" void kernel_launch(void* const* d_in, const int* in_sizes, int n_in,
                              void* d_out, int out_size, void* d_ws, size_t ws_size,
                              hipStream_t stream) {
  const float* query = (const float*)d_in[0];
  const float* key_  = (const float*)d_in[1];
  const float* value = (const float*)d_in[2];
  const float* Wq = (const float*)d_in[3];
  const float* bq = (const float*)d_in[4];
  const float* Wk = (const float*)d_in[5];
  const float* bk = (const float*)d_in[6];
  const float* Wv = (const float*)d_in[7];
  const float* bv = (const float*)d_in[8];
  const float* Wo = (const float*)d_in[9];
  const float* bo = (const float*)d_in[10];
  float* out = (float*)d_out;

  // workspace: 4 bf16 buffers of [16384, 1024] = 33.5 MB each (134 MB total)
  const size_t MN = (size_t)16384 * 1024;
  ushort* qp = (ushort*)d_ws;
  ushort* kp = qp + MN;
  ushort* vp = kp + MN;
  ushort* xp = vp + MN;

  const dim3 blk(256);
  const dim3 ggrid(128 * 8);  // (M/128) * (N/128)

  gemm_kernel<0, 1><<<ggrid, blk, 0, stream>>>(query, Wq, bq, qp, 1024, 1024);
  gemm_kernel<0, 1><<<ggrid, blk, 0, stream>>>(key_,  Wk, bk, kp, 1024, 1024);
  gemm_kernel<0, 1><<<ggrid, blk, 0, stream>>>(value, Wv, bv, vp, 1024, 1024);
  attn_kernel<<<dim3(1024), blk, 0, stream>>>(qp, kp, vp, xp);
  gemm_kernel<1, 0><<<ggrid, blk, 0, stream>>>(xp, Wo, bo, out, 1024, 1024);
}

// Round 2
// 408.671 us; speedup vs baseline: 1.0643x; 1.0643x over previous
//
#include <hip/hip_runtime.h>
#include <hip/hip_bf16.h>

typedef __attribute__((ext_vector_type(8))) __bf16 bf16x8;
typedef __attribute__((ext_vector_type(4))) float f32x4;

#define DEVI static __device__ __forceinline__

// ---- helpers ---------------------------------------------------------------

DEVI ushort f2bf(float f) {
  unsigned u = __builtin_bit_cast(unsigned, f);
  return (ushort)((u + 0x7fffu + ((u >> 16) & 1u)) >> 16);
}

union BF8 { unsigned u[4]; bf16x8 v; };

// 8 consecutive f32 -> 8 bf16 (RNE) via packed converts
DEVI bf16x8 cvt8(const float* __restrict__ p) {
  const f32x4 a = *(const f32x4*)p;
  const f32x4 b = *(const f32x4*)(p + 4);
  BF8 r;
  asm("v_cvt_pk_bf16_f32 %0, %1, %2" : "=v"(r.u[0]) : "v"(a.x), "v"(a.y));
  asm("v_cvt_pk_bf16_f32 %0, %1, %2" : "=v"(r.u[1]) : "v"(a.z), "v"(a.w));
  asm("v_cvt_pk_bf16_f32 %0, %1, %2" : "=v"(r.u[2]) : "v"(b.x), "v"(b.y));
  asm("v_cvt_pk_bf16_f32 %0, %1, %2" : "=v"(r.u[3]) : "v"(b.z), "v"(b.w));
  return r.v;
}

// async global->LDS, 16 bytes per lane
DEVI void gload16(const void* g, void* l) {
  __builtin_amdgcn_global_load_lds(
      (const __attribute__((address_space(1))) unsigned*)g,
      (__attribute__((address_space(3))) unsigned*)l, 16, 0, 0);
}

// ---- weight convert f32 -> bf16 --------------------------------------------

__global__ __launch_bounds__(256) void cvtw_kernel(
    const float* __restrict__ in, ushort* __restrict__ out, int n8) {
  const int i = blockIdx.x * blockDim.x + threadIdx.x;
  if (i < n8) *(bf16x8*)(out + (size_t)i * 8) = cvt8(in + (size_t)i * 8);
}

// ---- GEMM (f32 A): C[M,N] = A[M,K] @ W[N,K]^T + bias, out bf16 -------------
// 128x128 tile, BK=32, 256 threads, global_load_lds staging, swizzled LDS.

__global__ __launch_bounds__(256) void gemm_f32a(
    const float* __restrict__ A, const ushort* __restrict__ B,
    const float* __restrict__ bias, ushort* __restrict__ C, int N, int K) {
  __shared__ __align__(16) float As[128 * 32];   // 16 KB, rows of 8 x 16B units
  __shared__ __align__(16) ushort Bs[128 * 32];  // 8 KB, rows of 4 x 16B units
  const int tid = threadIdx.x, lane = tid & 63;
  const int wv = tid >> 6, wr = wv >> 1, wc = wv & 1;
  const int cc = lane & 15, cr = lane >> 4;
  const int ntiles = N >> 7;
  const size_t m0 = (size_t)(blockIdx.x / ntiles) * 128;
  const size_t n0 = (size_t)(blockIdx.x % ntiles) * 128;

  // staging: A tile 128x32 f32 = 1024 chunks of 16B; source pre-swizzled
  const float* asrc[4];
  float* adst[4];
#pragma unroll
  for (int i = 0; i < 4; ++i) {
    const int ch = tid + i * 256, row = ch >> 3, unit = ch & 7;
    asrc[i] = A + (m0 + row) * (size_t)K + (unit ^ (row & 7)) * 4;
    adst[i] = &As[ch * 4];
  }
  // B tile 128x32 bf16 = 512 chunks of 16B
  const ushort* bsrc[2];
  ushort* bdst[2];
#pragma unroll
  for (int i = 0; i < 2; ++i) {
    const int ch = tid + i * 256, row = ch >> 2, unit = ch & 3;
    bsrc[i] = B + (n0 + row) * (size_t)K + (unit ^ ((row >> 1) & 3)) * 8;
    bdst[i] = &Bs[ch * 8];
  }

  f32x4 acc[4][4] = {};
  for (int kt = 0; kt < K; kt += 32) {
#pragma unroll
    for (int i = 0; i < 4; ++i) gload16(asrc[i] + kt, adst[i]);
#pragma unroll
    for (int i = 0; i < 2; ++i) gload16(bsrc[i] + kt, bdst[i]);
    __syncthreads();
    bf16x8 af[4], bfr[4];
#pragma unroll
    for (int m = 0; m < 4; ++m) {
      const int row = wr * 64 + m * 16 + cc;
      const int p0 = (cr * 2) ^ (row & 7), p1 = (cr * 2 + 1) ^ (row & 7);
      const f32x4 x0 = *(const f32x4*)&As[row * 32 + p0 * 4];
      const f32x4 x1 = *(const f32x4*)&As[row * 32 + p1 * 4];
      BF8 r;
      asm("v_cvt_pk_bf16_f32 %0, %1, %2" : "=v"(r.u[0]) : "v"(x0.x), "v"(x0.y));
      asm("v_cvt_pk_bf16_f32 %0, %1, %2" : "=v"(r.u[1]) : "v"(x0.z), "v"(x0.w));
      asm("v_cvt_pk_bf16_f32 %0, %1, %2" : "=v"(r.u[2]) : "v"(x1.x), "v"(x1.y));
      asm("v_cvt_pk_bf16_f32 %0, %1, %2" : "=v"(r.u[3]) : "v"(x1.z), "v"(x1.w));
      af[m] = r.v;
    }
#pragma unroll
    for (int n = 0; n < 4; ++n) {
      const int row = wc * 64 + n * 16 + cc;
      const int p = cr ^ ((row >> 1) & 3);
      bfr[n] = *(const bf16x8*)&Bs[row * 32 + p * 8];
    }
#pragma unroll
    for (int m = 0; m < 4; ++m)
#pragma unroll
      for (int n = 0; n < 4; ++n)
        acc[m][n] =
            __builtin_amdgcn_mfma_f32_16x16x32_bf16(af[m], bfr[n], acc[m][n], 0, 0, 0);
    __syncthreads();
  }

#pragma unroll
  for (int n = 0; n < 4; ++n) {
    const size_t col = n0 + wc * 64 + n * 16 + cc;
    const float bval = bias[col];
#pragma unroll
    for (int m = 0; m < 4; ++m) {
      const size_t row0 = m0 + wr * 64 + m * 16 + cr * 4;
#pragma unroll
      for (int r = 0; r < 4; ++r)
        C[(row0 + r) * N + col] = f2bf(acc[m][n][r] + bval);
    }
  }
}

// ---- GEMM (bf16 A): C[M,N] = A[M,K] @ W[N,K]^T + bias, out f32 -------------

__global__ __launch_bounds__(256) void gemm_bf16a(
    const ushort* __restrict__ A, const ushort* __restrict__ B,
    const float* __restrict__ bias, float* __restrict__ C, int N, int K) {
  __shared__ __align__(16) ushort As[128 * 32];
  __shared__ __align__(16) ushort Bs[128 * 32];
  const int tid = threadIdx.x, lane = tid & 63;
  const int wv = tid >> 6, wr = wv >> 1, wc = wv & 1;
  const int cc = lane & 15, cr = lane >> 4;
  const int ntiles = N >> 7;
  const size_t m0 = (size_t)(blockIdx.x / ntiles) * 128;
  const size_t n0 = (size_t)(blockIdx.x % ntiles) * 128;

  const ushort* asrc[2];
  ushort* adst[2];
  const ushort* bsrc[2];
  ushort* bdst[2];
#pragma unroll
  for (int i = 0; i < 2; ++i) {
    const int ch = tid + i * 256, row = ch >> 2, unit = ch & 3;
    const int sw = (unit ^ ((row >> 1) & 3)) * 8;
    asrc[i] = A + (m0 + row) * (size_t)K + sw;
    adst[i] = &As[ch * 8];
    bsrc[i] = B + (n0 + row) * (size_t)K + sw;
    bdst[i] = &Bs[ch * 8];
  }

  f32x4 acc[4][4] = {};
  for (int kt = 0; kt < K; kt += 32) {
#pragma unroll
    for (int i = 0; i < 2; ++i) {
      gload16(asrc[i] + kt, adst[i]);
      gload16(bsrc[i] + kt, bdst[i]);
    }
    __syncthreads();
    bf16x8 af[4], bfr[4];
#pragma unroll
    for (int m = 0; m < 4; ++m) {
      const int row = wr * 64 + m * 16 + cc;
      af[m] = *(const bf16x8*)&As[row * 32 + (cr ^ ((row >> 1) & 3)) * 8];
    }
#pragma unroll
    for (int n = 0; n < 4; ++n) {
      const int row = wc * 64 + n * 16 + cc;
      bfr[n] = *(const bf16x8*)&Bs[row * 32 + (cr ^ ((row >> 1) & 3)) * 8];
    }
#pragma unroll
    for (int m = 0; m < 4; ++m)
#pragma unroll
      for (int n = 0; n < 4; ++n)
        acc[m][n] =
            __builtin_amdgcn_mfma_f32_16x16x32_bf16(af[m], bfr[n], acc[m][n], 0, 0, 0);
    __syncthreads();
  }

#pragma unroll
  for (int n = 0; n < 4; ++n) {
    const size_t col = n0 + wc * 64 + n * 16 + cc;
    const float bval = bias[col];
#pragma unroll
    for (int m = 0; m < 4; ++m) {
      const size_t row0 = m0 + wr * 64 + m * 16 + cr * 4;
#pragma unroll
      for (int r = 0; r < 4; ++r)
        C[(row0 + r) * N + col] = acc[m][n][r] + bval;
    }
  }
}

// ---- windowed attention ----------------------------------------------------
// grid = B*H*NW = 1024 blocks, 256 threads (4 waves x 64 q-rows).
// q/k/v: bf16 [B*S, D] with col = h*64+dk. Output written in-place over q.

__global__ __launch_bounds__(256) void attn_kernel(
    const ushort* __restrict__ q, const ushort* __restrict__ k,
    const ushort* __restrict__ v, ushort* __restrict__ x) {
  __shared__ ushort Ks[256 * 72];       // K tile, padded stride 72
  __shared__ ushort Vt[64 * 264];       // V transposed [dk][s], padded stride 264
  __shared__ ushort Pw[4][16 * 264];    // per-wave P chunk [16 q-rows][256 cols]
  const int bid = blockIdx.x;
  const int w = bid & 15, h = (bid >> 4) & 15, b = bid >> 8;
  const int tid = threadIdx.x, lane = tid & 63, wv = tid >> 6;
  const int cc = lane & 15, cr = lane >> 4;
  const size_t base = ((size_t)b * 4096 + (size_t)w * 256) * 1024 + h * 64;

  // stage K: [256 rows][64 cols] -> Ks[row*72 + c]
#pragma unroll
  for (int i = 0; i < 8; ++i) {
    const int ch = i * 256 + tid;          // 2048 chunks of 8
    const int row = ch >> 3, kc = ch & 7;
    bf16x8 val = *(const bf16x8*)(k + base + (size_t)row * 1024 + kc * 8);
    *(bf16x8*)&Ks[row * 72 + kc * 8] = val;
  }
  // stage V transposed: Vt[dk*264 + s]
  {
    const ushort* vp = v + base + (size_t)tid * 1024;
#pragma unroll
    for (int j = 0; j < 8; ++j) {
      bf16x8 vv = *(const bf16x8*)(vp + j * 8);
#pragma unroll
      for (int e = 0; e < 8; ++e)
        Vt[(j * 8 + e) * 264 + tid] = __builtin_bit_cast(ushort, (__bf16)vv[e]);
    }
  }
  __syncthreads();

  ushort* Pp = Pw[wv];
  for (int c = 0; c < 4; ++c) {
    const int qrow0 = wv * 64 + c * 16;
    const ushort* qp = q + base + (size_t)(qrow0 + cc) * 1024 + cr * 8;
    const bf16x8 qf0 = *(const bf16x8*)qp;
    const bf16x8 qf1 = *(const bf16x8*)(qp + 32);

    f32x4 sc[16];
#pragma unroll
    for (int cb = 0; cb < 16; ++cb) {
      const bf16x8 b0 = *(const bf16x8*)&Ks[(cb * 16 + cc) * 72 + cr * 8];
      const bf16x8 b1 = *(const bf16x8*)&Ks[(cb * 16 + cc) * 72 + 32 + cr * 8];
      f32x4 z = {0.f, 0.f, 0.f, 0.f};
      z = __builtin_amdgcn_mfma_f32_16x16x32_bf16(qf0, b0, z, 0, 0, 0);
      z = __builtin_amdgcn_mfma_f32_16x16x32_bf16(qf1, b1, z, 0, 0, 0);
      sc[cb] = z;
    }

    float inv[4];
#pragma unroll
    for (int r = 0; r < 4; ++r) {
      float mx = -1e30f;
#pragma unroll
      for (int cb = 0; cb < 16; ++cb) mx = fmaxf(mx, sc[cb][r]);
      mx = fmaxf(mx, __shfl_xor(mx, 1));
      mx = fmaxf(mx, __shfl_xor(mx, 2));
      mx = fmaxf(mx, __shfl_xor(mx, 4));
      mx = fmaxf(mx, __shfl_xor(mx, 8));
      float sum = 0.f;
#pragma unroll
      for (int cb = 0; cb < 16; ++cb) {
        const float p = __expf((sc[cb][r] - mx) * 0.125f);
        sc[cb][r] = p;
        sum += p;
      }
      sum += __shfl_xor(sum, 1);
      sum += __shfl_xor(sum, 2);
      sum += __shfl_xor(sum, 4);
      sum += __shfl_xor(sum, 8);
      inv[r] = 1.f / sum;
    }

#pragma unroll
    for (int r = 0; r < 4; ++r)
#pragma unroll
      for (int cb = 0; cb < 16; ++cb)
        Pp[(cr * 4 + r) * 264 + cb * 16 + cc] = f2bf(sc[cb][r]);

    bf16x8 pf[8];
#pragma unroll
    for (int ks = 0; ks < 8; ++ks)
      pf[ks] = *(const bf16x8*)&Pp[cc * 264 + ks * 32 + cr * 8];
    f32x4 o[4] = {};
#pragma unroll
    for (int db = 0; db < 4; ++db)
#pragma unroll
      for (int ks = 0; ks < 8; ++ks) {
        const bf16x8 bv = *(const bf16x8*)&Vt[(db * 16 + cc) * 264 + ks * 32 + cr * 8];
        o[db] = __builtin_amdgcn_mfma_f32_16x16x32_bf16(pf[ks], bv, o[db], 0, 0, 0);
      }

#pragma unroll
    for (int db = 0; db < 4; ++db)
#pragma unroll
      for (int r = 0; r < 4; ++r) {
        const int qr = qrow0 + cr * 4 + r;
        x[base + (size_t)qr * 1024 + db * 16 + cc] = f2bf(o[db][r] * inv[r]);
      }
  }
}

// ---- launch ----------------------------------------------------------------

extern "C" void kernel_launch(void* const* d_in, const int* in_sizes, int n_in,
                              void* d_out, int out_size, void* d_ws, size_t ws_size,
                              hipStream_t stream) {
  const float* query = (const float*)d_in[0];
  const float* key_  = (const float*)d_in[1];
  const float* value = (const float*)d_in[2];
  const float* Wq = (const float*)d_in[3];
  const float* bq = (const float*)d_in[4];
  const float* Wk = (const float*)d_in[5];
  const float* bk = (const float*)d_in[6];
  const float* Wv = (const float*)d_in[7];
  const float* bv = (const float*)d_in[8];
  const float* Wo = (const float*)d_in[9];
  const float* bo = (const float*)d_in[10];
  float* out = (float*)d_out;

  // ws: qp/kp/vp bf16 [16384,1024] (33.5 MB each) + 4 bf16 weights (2 MB each)
  const size_t MN = (size_t)16384 * 1024;
  const size_t WN = (size_t)1024 * 1024;
  ushort* qp = (ushort*)d_ws;
  ushort* kp = qp + MN;
  ushort* vp = kp + MN;
  ushort* wqb = vp + MN;
  ushort* wkb = wqb + WN;
  ushort* wvb = wkb + WN;
  ushort* wob = wvb + WN;

  const dim3 blk(256);
  const dim3 ggrid(128 * 8);  // (M/128) * (N/128)
  const int wn8 = (int)(WN / 8);

  cvtw_kernel<<<dim3(wn8 / 256), blk, 0, stream>>>(Wq, wqb, wn8);
  cvtw_kernel<<<dim3(wn8 / 256), blk, 0, stream>>>(Wk, wkb, wn8);
  cvtw_kernel<<<dim3(wn8 / 256), blk, 0, stream>>>(Wv, wvb, wn8);
  cvtw_kernel<<<dim3(wn8 / 256), blk, 0, stream>>>(Wo, wob, wn8);

  gemm_f32a<<<ggrid, blk, 0, stream>>>(query, wqb, bq, qp, 1024, 1024);
  gemm_f32a<<<ggrid, blk, 0, stream>>>(key_,  wkb, bk, kp, 1024, 1024);
  gemm_f32a<<<ggrid, blk, 0, stream>>>(value, wvb, bv, vp, 1024, 1024);

  attn_kernel<<<dim3(1024), blk, 0, stream>>>(qp, kp, vp, qp /*in-place*/);

  gemm_bf16a<<<ggrid, blk, 0, stream>>>(qp, wob, bo, out, 1024, 1024);
}

// Round 4
// 402.328 us; speedup vs baseline: 1.0811x; 1.0158x over previous
//
#include <hip/hip_runtime.h>
#include <hip/hip_bf16.h>

typedef __attribute__((ext_vector_type(8))) __bf16 bf16x8;
typedef __attribute__((ext_vector_type(4))) float f32x4;

#define DEVI static __device__ __forceinline__

// ---- helpers ---------------------------------------------------------------

DEVI ushort f2bf(float f) {
  unsigned u = __builtin_bit_cast(unsigned, f);
  return (ushort)((u + 0x7fffu + ((u >> 16) & 1u)) >> 16);
}

union BF8 { unsigned u[4]; bf16x8 v; };

// 8 consecutive f32 -> 8 bf16 (RNE) via packed converts
DEVI bf16x8 cvt8(const float* __restrict__ p) {
  const f32x4 a = *(const f32x4*)p;
  const f32x4 b = *(const f32x4*)(p + 4);
  BF8 r;
  asm("v_cvt_pk_bf16_f32 %0, %1, %2" : "=v"(r.u[0]) : "v"(a.x), "v"(a.y));
  asm("v_cvt_pk_bf16_f32 %0, %1, %2" : "=v"(r.u[1]) : "v"(a.z), "v"(a.w));
  asm("v_cvt_pk_bf16_f32 %0, %1, %2" : "=v"(r.u[2]) : "v"(b.x), "v"(b.y));
  asm("v_cvt_pk_bf16_f32 %0, %1, %2" : "=v"(r.u[3]) : "v"(b.z), "v"(b.w));
  return r.v;
}

// async global->LDS, 16 bytes per lane
DEVI void gload16(const void* g, void* l) {
  __builtin_amdgcn_global_load_lds(
      (const __attribute__((address_space(1))) unsigned*)g,
      (__attribute__((address_space(3))) unsigned*)l, 16, 0, 0);
}

// XCD-aware bijective swizzle (requires nwg % 8 == 0): all n-tiles of an
// m-tile land on one XCD so the A-panel is fetched once per XCD L2.
DEVI int xcd_swizzle(int bid, int nwg) {
  return (bid & 7) * (nwg >> 3) + (bid >> 3);
}

// ---- weight convert f32 -> bf16 --------------------------------------------

__global__ __launch_bounds__(256) void cvtw_kernel(
    const float* __restrict__ in, ushort* __restrict__ out, int n8) {
  const int i = blockIdx.x * blockDim.x + threadIdx.x;
  if (i < n8) *(bf16x8*)(out + (size_t)i * 8) = cvt8(in + (size_t)i * 8);
}

// ---- GEMM (f32 A): C[M,N] = A[M,K] @ W[N,K]^T + bias, out bf16 -------------
// 128x128 tile, BK=32, 256 threads, global_load_lds staging, swizzled LDS.

__global__ __launch_bounds__(256) void gemm_f32a(
    const float* __restrict__ A, const ushort* __restrict__ B,
    const float* __restrict__ bias, ushort* __restrict__ C, int N, int K) {
  __shared__ __align__(16) float As[128 * 32];   // 16 KB, rows of 8 x 16B units
  __shared__ __align__(16) ushort Bs[128 * 32];  // 8 KB, rows of 4 x 16B units
  const int tid = threadIdx.x, lane = tid & 63;
  const int wv = tid >> 6, wr = wv >> 1, wc = wv & 1;
  const int cc = lane & 15, cr = lane >> 4;
  const int ntiles = N >> 7;
  const int work = xcd_swizzle(blockIdx.x, gridDim.x);
  const size_t m0 = (size_t)(work / ntiles) * 128;
  const size_t n0 = (size_t)(work % ntiles) * 128;

  // staging: A tile 128x32 f32 = 1024 chunks of 16B; source pre-swizzled
  const float* asrc[4];
  float* adst[4];
#pragma unroll
  for (int i = 0; i < 4; ++i) {
    const int ch = tid + i * 256, row = ch >> 3, unit = ch & 7;
    asrc[i] = A + (m0 + row) * (size_t)K + (unit ^ (row & 7)) * 4;
    adst[i] = &As[ch * 4];
  }
  // B tile 128x32 bf16 = 512 chunks of 16B
  const ushort* bsrc[2];
  ushort* bdst[2];
#pragma unroll
  for (int i = 0; i < 2; ++i) {
    const int ch = tid + i * 256, row = ch >> 2, unit = ch & 3;
    bsrc[i] = B + (n0 + row) * (size_t)K + (unit ^ ((row >> 1) & 3)) * 8;
    bdst[i] = &Bs[ch * 8];
  }

  f32x4 acc[4][4] = {};
  for (int kt = 0; kt < K; kt += 32) {
#pragma unroll
    for (int i = 0; i < 4; ++i) gload16(asrc[i] + kt, adst[i]);
#pragma unroll
    for (int i = 0; i < 2; ++i) gload16(bsrc[i] + kt, bdst[i]);
    __syncthreads();
    bf16x8 af[4], bfr[4];
#pragma unroll
    for (int m = 0; m < 4; ++m) {
      const int row = wr * 64 + m * 16 + cc;
      const int p0 = (cr * 2) ^ (row & 7), p1 = (cr * 2 + 1) ^ (row & 7);
      const f32x4 x0 = *(const f32x4*)&As[row * 32 + p0 * 4];
      const f32x4 x1 = *(const f32x4*)&As[row * 32 + p1 * 4];
      BF8 r;
      asm("v_cvt_pk_bf16_f32 %0, %1, %2" : "=v"(r.u[0]) : "v"(x0.x), "v"(x0.y));
      asm("v_cvt_pk_bf16_f32 %0, %1, %2" : "=v"(r.u[1]) : "v"(x0.z), "v"(x0.w));
      asm("v_cvt_pk_bf16_f32 %0, %1, %2" : "=v"(r.u[2]) : "v"(x1.x), "v"(x1.y));
      asm("v_cvt_pk_bf16_f32 %0, %1, %2" : "=v"(r.u[3]) : "v"(x1.z), "v"(x1.w));
      af[m] = r.v;
    }
#pragma unroll
    for (int n = 0; n < 4; ++n) {
      const int row = wc * 64 + n * 16 + cc;
      const int p = cr ^ ((row >> 1) & 3);
      bfr[n] = *(const bf16x8*)&Bs[row * 32 + p * 8];
    }
#pragma unroll
    for (int m = 0; m < 4; ++m)
#pragma unroll
      for (int n = 0; n < 4; ++n)
        acc[m][n] =
            __builtin_amdgcn_mfma_f32_16x16x32_bf16(af[m], bfr[n], acc[m][n], 0, 0, 0);
    __syncthreads();
  }

#pragma unroll
  for (int n = 0; n < 4; ++n) {
    const size_t col = n0 + wc * 64 + n * 16 + cc;
    const float bval = bias[col];
#pragma unroll
    for (int m = 0; m < 4; ++m) {
      const size_t row0 = m0 + wr * 64 + m * 16 + cr * 4;
#pragma unroll
      for (int r = 0; r < 4; ++r)
        C[(row0 + r) * N + col] = f2bf(acc[m][n][r] + bval);
    }
  }
}

// ---- GEMM (bf16 A): C[M,N] = A[M,K] @ W[N,K]^T + bias, out f32 -------------

__global__ __launch_bounds__(256) void gemm_bf16a(
    const ushort* __restrict__ A, const ushort* __restrict__ B,
    const float* __restrict__ bias, float* __restrict__ C, int N, int K) {
  __shared__ __align__(16) ushort As[128 * 32];
  __shared__ __align__(16) ushort Bs[128 * 32];
  const int tid = threadIdx.x, lane = tid & 63;
  const int wv = tid >> 6, wr = wv >> 1, wc = wv & 1;
  const int cc = lane & 15, cr = lane >> 4;
  const int ntiles = N >> 7;
  const int work = xcd_swizzle(blockIdx.x, gridDim.x);
  const size_t m0 = (size_t)(work / ntiles) * 128;
  const size_t n0 = (size_t)(work % ntiles) * 128;

  const ushort* asrc[2];
  ushort* adst[2];
  const ushort* bsrc[2];
  ushort* bdst[2];
#pragma unroll
  for (int i = 0; i < 2; ++i) {
    const int ch = tid + i * 256, row = ch >> 2, unit = ch & 3;
    const int sw = (unit ^ ((row >> 1) & 3)) * 8;
    asrc[i] = A + (m0 + row) * (size_t)K + sw;
    adst[i] = &As[ch * 8];
    bsrc[i] = B + (n0 + row) * (size_t)K + sw;
    bdst[i] = &Bs[ch * 8];
  }

  f32x4 acc[4][4] = {};
  for (int kt = 0; kt < K; kt += 32) {
#pragma unroll
    for (int i = 0; i < 2; ++i) {
      gload16(asrc[i] + kt, adst[i]);
      gload16(bsrc[i] + kt, bdst[i]);
    }
    __syncthreads();
    bf16x8 af[4], bfr[4];
#pragma unroll
    for (int m = 0; m < 4; ++m) {
      const int row = wr * 64 + m * 16 + cc;
      af[m] = *(const bf16x8*)&As[row * 32 + (cr ^ ((row >> 1) & 3)) * 8];
    }
#pragma unroll
    for (int n = 0; n < 4; ++n) {
      const int row = wc * 64 + n * 16 + cc;
      bfr[n] = *(const bf16x8*)&Bs[row * 32 + (cr ^ ((row >> 1) & 3)) * 8];
    }
#pragma unroll
    for (int m = 0; m < 4; ++m)
#pragma unroll
      for (int n = 0; n < 4; ++n)
        acc[m][n] =
            __builtin_amdgcn_mfma_f32_16x16x32_bf16(af[m], bfr[n], acc[m][n], 0, 0, 0);
    __syncthreads();
  }

#pragma unroll
  for (int n = 0; n < 4; ++n) {
    const size_t col = n0 + wc * 64 + n * 16 + cc;
    const float bval = bias[col];
#pragma unroll
    for (int m = 0; m < 4; ++m) {
      const size_t row0 = m0 + wr * 64 + m * 16 + cr * 4;
#pragma unroll
      for (int r = 0; r < 4; ++r)
        C[(row0 + r) * N + col] = acc[m][n][r] + bval;
    }
  }
}

// ---- windowed attention ----------------------------------------------------
// grid = B*H*NW = 1024 blocks, 256 threads (4 waves x 64 q-rows).
// q/k/v: bf16 [B*S, D] with col = h*64+dk. Output written in-place over q.

__global__ __launch_bounds__(256) void attn_kernel(
    const ushort* __restrict__ q, const ushort* __restrict__ k,
    const ushort* __restrict__ v, ushort* __restrict__ x) {
  __shared__ ushort Ks[256 * 72];       // K tile, padded stride 72
  __shared__ ushort Vt[64 * 264];       // V transposed [dk][s], padded stride 264
  __shared__ ushort Pw[4][16 * 264];    // per-wave P chunk [16 q-rows][256 cols]
  const int bid = blockIdx.x;
  const int w = bid & 15, h = (bid >> 4) & 15, b = bid >> 8;
  const int tid = threadIdx.x, lane = tid & 63, wv = tid >> 6;
  const int cc = lane & 15, cr = lane >> 4;
  const size_t base = ((size_t)b * 4096 + (size_t)w * 256) * 1024 + h * 64;

  // stage K: [256 rows][64 cols] -> Ks[row*72 + c]
#pragma unroll
  for (int i = 0; i < 8; ++i) {
    const int ch = i * 256 + tid;          // 2048 chunks of 8
    const int row = ch >> 3, kc = ch & 7;
    bf16x8 val = *(const bf16x8*)(k + base + (size_t)row * 1024 + kc * 8);
    *(bf16x8*)&Ks[row * 72 + kc * 8] = val;
  }
  // stage V transposed: Vt[dk*264 + s]
  {
    const ushort* vp = v + base + (size_t)tid * 1024;
#pragma unroll
    for (int j = 0; j < 8; ++j) {
      bf16x8 vv = *(const bf16x8*)(vp + j * 8);
#pragma unroll
      for (int e = 0; e < 8; ++e)
        Vt[(j * 8 + e) * 264 + tid] = __builtin_bit_cast(ushort, (__bf16)vv[e]);
    }
  }
  __syncthreads();

  ushort* Pp = Pw[wv];
  for (int c = 0; c < 4; ++c) {
    const int qrow0 = wv * 64 + c * 16;
    const ushort* qp = q + base + (size_t)(qrow0 + cc) * 1024 + cr * 8;
    const bf16x8 qf0 = *(const bf16x8*)qp;
    const bf16x8 qf1 = *(const bf16x8*)(qp + 32);

    f32x4 sc[16];
#pragma unroll
    for (int cb = 0; cb < 16; ++cb) {
      const bf16x8 b0 = *(const bf16x8*)&Ks[(cb * 16 + cc) * 72 + cr * 8];
      const bf16x8 b1 = *(const bf16x8*)&Ks[(cb * 16 + cc) * 72 + 32 + cr * 8];
      f32x4 z = {0.f, 0.f, 0.f, 0.f};
      z = __builtin_amdgcn_mfma_f32_16x16x32_bf16(qf0, b0, z, 0, 0, 0);
      z = __builtin_amdgcn_mfma_f32_16x16x32_bf16(qf1, b1, z, 0, 0, 0);
      sc[cb] = z;
    }

    float inv[4];
#pragma unroll
    for (int r = 0; r < 4; ++r) {
      float mx = -1e30f;
#pragma unroll
      for (int cb = 0; cb < 16; ++cb) mx = fmaxf(mx, sc[cb][r]);
      mx = fmaxf(mx, __shfl_xor(mx, 1));
      mx = fmaxf(mx, __shfl_xor(mx, 2));
      mx = fmaxf(mx, __shfl_xor(mx, 4));
      mx = fmaxf(mx, __shfl_xor(mx, 8));
      float sum = 0.f;
#pragma unroll
      for (int cb = 0; cb < 16; ++cb) {
        const float p = __expf((sc[cb][r] - mx) * 0.125f);
        sc[cb][r] = p;
        sum += p;
      }
      sum += __shfl_xor(sum, 1);
      sum += __shfl_xor(sum, 2);
      sum += __shfl_xor(sum, 4);
      sum += __shfl_xor(sum, 8);
      inv[r] = 1.f / sum;
    }

#pragma unroll
    for (int r = 0; r < 4; ++r)
#pragma unroll
      for (int cb = 0; cb < 16; ++cb)
        Pp[(cr * 4 + r) * 264 + cb * 16 + cc] = f2bf(sc[cb][r]);

    bf16x8 pf[8];
#pragma unroll
    for (int ks = 0; ks < 8; ++ks)
      pf[ks] = *(const bf16x8*)&Pp[cc * 264 + ks * 32 + cr * 8];
    f32x4 o[4] = {};
#pragma unroll
    for (int db = 0; db < 4; ++db)
#pragma unroll
      for (int ks = 0; ks < 8; ++ks) {
        const bf16x8 bv = *(const bf16x8*)&Vt[(db * 16 + cc) * 264 + ks * 32 + cr * 8];
        o[db] = __builtin_amdgcn_mfma_f32_16x16x32_bf16(pf[ks], bv, o[db], 0, 0, 0);
      }

#pragma unroll
    for (int db = 0; db < 4; ++db)
#pragma unroll
      for (int r = 0; r < 4; ++r) {
        const int qr = qrow0 + cr * 4 + r;
        x[base + (size_t)qr * 1024 + db * 16 + cc] = f2bf(o[db][r] * inv[r]);
      }
  }
}

// ---- launch ----------------------------------------------------------------

extern "C" void kernel_launch(void* const* d_in, const int* in_sizes, int n_in,
                              void* d_out, int out_size, void* d_ws, size_t ws_size,
                              hipStream_t stream) {
  const float* query = (const float*)d_in[0];
  const float* key_  = (const float*)d_in[1];
  const float* value = (const float*)d_in[2];
  const float* Wq = (const float*)d_in[3];
  const float* bq = (const float*)d_in[4];
  const float* Wk = (const float*)d_in[5];
  const float* bk = (const float*)d_in[6];
  const float* Wv = (const float*)d_in[7];
  const float* bv = (const float*)d_in[8];
  const float* Wo = (const float*)d_in[9];
  const float* bo = (const float*)d_in[10];
  float* out = (float*)d_out;

  // ws: qp/kp/vp bf16 [16384,1024] (33.5 MB each) + 4 bf16 weights (2 MB each)
  const size_t MN = (size_t)16384 * 1024;
  const size_t WN = (size_t)1024 * 1024;
  ushort* qp = (ushort*)d_ws;
  ushort* kp = qp + MN;
  ushort* vp = kp + MN;
  ushort* wqb = vp + MN;
  ushort* wkb = wqb + WN;
  ushort* wvb = wkb + WN;
  ushort* wob = wvb + WN;

  const dim3 blk(256);
  const dim3 ggrid(128 * 8);  // (M/128) * (N/128)
  const int wn8 = (int)(WN / 8);

  cvtw_kernel<<<dim3(wn8 / 256), blk, 0, stream>>>(Wq, wqb, wn8);
  cvtw_kernel<<<dim3(wn8 / 256), blk, 0, stream>>>(Wk, wkb, wn8);
  cvtw_kernel<<<dim3(wn8 / 256), blk, 0, stream>>>(Wv, wvb, wn8);
  cvtw_kernel<<<dim3(wn8 / 256), blk, 0, stream>>>(Wo, wob, wn8);

  gemm_f32a<<<ggrid, blk, 0, stream>>>(query, wqb, bq, qp, 1024, 1024);
  gemm_f32a<<<ggrid, blk, 0, stream>>>(key_,  wkb, bk, kp, 1024, 1024);
  gemm_f32a<<<ggrid, blk, 0, stream>>>(value, wvb, bv, vp, 1024, 1024);

  attn_kernel<<<dim3(1024), blk, 0, stream>>>(qp, kp, vp, qp /*in-place*/);

  gemm_bf16a<<<ggrid, blk, 0, stream>>>(qp, wob, bo, out, 1024, 1024);
}

// Round 5
// 363.077 us; speedup vs baseline: 1.1980x; 1.1081x over previous
//
#include <hip/hip_runtime.h>
#include <hip/hip_bf16.h>

typedef __attribute__((ext_vector_type(8))) __bf16 bf16x8;
typedef __attribute__((ext_vector_type(4))) float f32x4;

#define DEVI static __device__ __forceinline__

// ---- helpers ---------------------------------------------------------------

DEVI ushort f2bf(float f) {
  unsigned u = __builtin_bit_cast(unsigned, f);
  return (ushort)((u + 0x7fffu + ((u >> 16) & 1u)) >> 16);
}

union BF8 { unsigned u[4]; bf16x8 v; };

// 8 consecutive f32 -> 8 bf16 (RNE) via packed converts
DEVI bf16x8 cvt8(const float* __restrict__ p) {
  const f32x4 a = *(const f32x4*)p;
  const f32x4 b = *(const f32x4*)(p + 4);
  BF8 r;
  asm("v_cvt_pk_bf16_f32 %0, %1, %2" : "=v"(r.u[0]) : "v"(a.x), "v"(a.y));
  asm("v_cvt_pk_bf16_f32 %0, %1, %2" : "=v"(r.u[1]) : "v"(a.z), "v"(a.w));
  asm("v_cvt_pk_bf16_f32 %0, %1, %2" : "=v"(r.u[2]) : "v"(b.x), "v"(b.y));
  asm("v_cvt_pk_bf16_f32 %0, %1, %2" : "=v"(r.u[3]) : "v"(b.z), "v"(b.w));
  return r.v;
}

// async global->LDS, 16 bytes per lane
DEVI void gload16(const void* g, void* l) {
  __builtin_amdgcn_global_load_lds(
      (const __attribute__((address_space(1))) unsigned*)g,
      (__attribute__((address_space(3))) unsigned*)l, 16, 0, 0);
}

// XCD-aware bijective swizzle (requires nwg % 8 == 0)
DEVI int xcd_swizzle(int bid, int nwg) {
  return (bid & 7) * (nwg >> 3) + (bid >> 3);
}

// ---- fused f32 -> bf16 convert: q, k, v, and 4 weight matrices -------------

__global__ __launch_bounds__(256) void cvt_all(
    const float* __restrict__ q, const float* __restrict__ k,
    const float* __restrict__ v, const float* __restrict__ wq,
    const float* __restrict__ wk, const float* __restrict__ wv,
    const float* __restrict__ wo, ushort* __restrict__ oq,
    ushort* __restrict__ ok2, ushort* __restrict__ ov,
    ushort* __restrict__ owq, ushort* __restrict__ owk,
    ushort* __restrict__ owv, ushort* __restrict__ owo) {
  const unsigned QN8 = 1u << 21;  // 16M elems / 8
  const unsigned WN8 = 1u << 17;  // 1M elems / 8
  const unsigned total = 3 * QN8 + 4 * WN8;
  for (unsigned i = blockIdx.x * 256 + threadIdx.x; i < total;
       i += gridDim.x * 256) {
    const float* src;
    ushort* dst;
    unsigned off;
    if (i < 3 * QN8) {
      const unsigned s = i >> 21;
      off = i & (QN8 - 1);
      src = s == 0 ? q : (s == 1 ? k : v);
      dst = s == 0 ? oq : (s == 1 ? ok2 : ov);
    } else {
      const unsigned j = i - 3 * QN8;
      const unsigned s = j >> 17;
      off = j & (WN8 - 1);
      src = s == 0 ? wq : (s == 1 ? wk : (s == 2 ? wv : wo));
      dst = s == 0 ? owq : (s == 1 ? owk : (s == 2 ? owv : owo));
    }
    *(bf16x8*)(dst + (size_t)off * 8) = cvt8(src + (size_t)off * 8);
  }
}

// ---- GEMM (bf16 x bf16): C[M,N] = A @ W^T + bias ---------------------------
// 128x128 tile, BK=32, 256 threads, double-buffered LDS with prefetch:
// STAGE(t+1) issued before computing tile t; counted vmcnt(4) + raw s_barrier
// keeps next-tile loads in flight under compute (T3 minimum 2-phase).

template <int OUT_BF16>
__global__ __launch_bounds__(256) void gemm_2ph(
    const ushort* __restrict__ A, const ushort* __restrict__ B,
    const float* __restrict__ bias, void* __restrict__ Cp, int N, int K) {
  __shared__ __align__(16) ushort As[2][128 * 32];
  __shared__ __align__(16) ushort Bs[2][128 * 32];
  const int tid = threadIdx.x, lane = tid & 63;
  const int wv = tid >> 6, wr = wv >> 1, wc = wv & 1;
  const int cc = lane & 15, cr = lane >> 4;
  const int ntiles = N >> 7;
  const int work = xcd_swizzle(blockIdx.x, gridDim.x);
  const size_t m0 = (size_t)(work / ntiles) * 128;
  const size_t n0 = (size_t)(work % ntiles) * 128;

  // staging addresses: 512 chunks of 16B per tile; source pre-swizzled so
  // linear LDS dest + swizzled ds_read are conflict-free (both-sides rule)
  const int ch0 = tid, ch1 = tid + 256;
  const int row0 = ch0 >> 2, u0 = ch0 & 3;
  const int row1 = ch1 >> 2, u1 = ch1 & 3;
  const int sw0 = (u0 ^ ((row0 >> 1) & 3)) * 8;
  const int sw1 = (u1 ^ ((row1 >> 1) & 3)) * 8;
  const ushort* a0 = A + (m0 + row0) * (size_t)K + sw0;
  const ushort* a1 = A + (m0 + row1) * (size_t)K + sw1;
  const ushort* b0 = B + (n0 + row0) * (size_t)K + sw0;
  const ushort* b1 = B + (n0 + row1) * (size_t)K + sw1;

  auto stage = [&](int bf, int kt) {
    ushort* ab = &As[bf][0];
    ushort* bb = &Bs[bf][0];
    gload16(a0 + kt, ab + ch0 * 8);
    gload16(a1 + kt, ab + ch1 * 8);
    gload16(b0 + kt, bb + ch0 * 8);
    gload16(b1 + kt, bb + ch1 * 8);
  };

  f32x4 acc[4][4] = {};
  const int nt = K >> 5;

  stage(0, 0);
  for (int t = 0; t < nt; ++t) {
    const int cur = t & 1;
    if (t + 1 < nt) {
      stage(cur ^ 1, (t + 1) << 5);
      asm volatile("s_waitcnt vmcnt(4)" ::: "memory");  // cur's 4 loads done
    } else {
      asm volatile("s_waitcnt vmcnt(0)" ::: "memory");
    }
    __builtin_amdgcn_s_barrier();           // all waves' cur loads landed
    asm volatile("" ::: "memory");

    bf16x8 af[4], bfr[4];
#pragma unroll
    for (int m = 0; m < 4; ++m) {
      const int row = wr * 64 + m * 16 + cc;
      af[m] = *(const bf16x8*)&As[cur][row * 32 + (cr ^ ((row >> 1) & 3)) * 8];
    }
#pragma unroll
    for (int n = 0; n < 4; ++n) {
      const int row = wc * 64 + n * 16 + cc;
      bfr[n] = *(const bf16x8*)&Bs[cur][row * 32 + (cr ^ ((row >> 1) & 3)) * 8];
    }
#pragma unroll
    for (int m = 0; m < 4; ++m)
#pragma unroll
      for (int n = 0; n < 4; ++n)
        acc[m][n] =
            __builtin_amdgcn_mfma_f32_16x16x32_bf16(af[m], bfr[n], acc[m][n], 0, 0, 0);

    asm volatile("" ::: "memory");
    __builtin_amdgcn_s_barrier();           // reads done before buf reuse
  }

#pragma unroll
  for (int n = 0; n < 4; ++n) {
    const size_t col = n0 + wc * 64 + n * 16 + cc;
    const float bval = bias[col];
#pragma unroll
    for (int m = 0; m < 4; ++m) {
      const size_t row0_ = m0 + wr * 64 + m * 16 + cr * 4;
#pragma unroll
      for (int r = 0; r < 4; ++r) {
        const float val = acc[m][n][r] + bval;
        if constexpr (OUT_BF16)
          ((ushort*)Cp)[(row0_ + r) * N + col] = f2bf(val);
        else
          ((float*)Cp)[(row0_ + r) * N + col] = val;
      }
    }
  }
}

// ---- windowed attention ----------------------------------------------------
// grid = B*H*NW = 1024 blocks, 256 threads (4 waves x 64 q-rows).
// q/k/v: bf16 [B*S, D] with col = h*64+dk. Output written in-place over q.

__global__ __launch_bounds__(256) void attn_kernel(
    const ushort* __restrict__ q, const ushort* __restrict__ k,
    const ushort* __restrict__ v, ushort* __restrict__ x) {
  __shared__ ushort Ks[256 * 72];       // K tile, padded stride 72
  __shared__ ushort Vt[64 * 264];       // V transposed [dk][s], padded stride 264
  __shared__ ushort Pw[4][16 * 264];    // per-wave P chunk [16 q-rows][256 cols]
  const int bid = blockIdx.x;
  const int w = bid & 15, h = (bid >> 4) & 15, b = bid >> 8;
  const int tid = threadIdx.x, lane = tid & 63, wv = tid >> 6;
  const int cc = lane & 15, cr = lane >> 4;
  const size_t base = ((size_t)b * 4096 + (size_t)w * 256) * 1024 + h * 64;

#pragma unroll
  for (int i = 0; i < 8; ++i) {
    const int ch = i * 256 + tid;
    const int row = ch >> 3, kc = ch & 7;
    bf16x8 val = *(const bf16x8*)(k + base + (size_t)row * 1024 + kc * 8);
    *(bf16x8*)&Ks[row * 72 + kc * 8] = val;
  }
  {
    const ushort* vp = v + base + (size_t)tid * 1024;
#pragma unroll
    for (int j = 0; j < 8; ++j) {
      bf16x8 vvv = *(const bf16x8*)(vp + j * 8);
#pragma unroll
      for (int e = 0; e < 8; ++e)
        Vt[(j * 8 + e) * 264 + tid] = __builtin_bit_cast(ushort, (__bf16)vvv[e]);
    }
  }
  __syncthreads();

  ushort* Pp = Pw[wv];
  for (int c = 0; c < 4; ++c) {
    const int qrow0 = wv * 64 + c * 16;
    const ushort* qp = q + base + (size_t)(qrow0 + cc) * 1024 + cr * 8;
    const bf16x8 qf0 = *(const bf16x8*)qp;
    const bf16x8 qf1 = *(const bf16x8*)(qp + 32);

    f32x4 sc[16];
#pragma unroll
    for (int cb = 0; cb < 16; ++cb) {
      const bf16x8 kb0 = *(const bf16x8*)&Ks[(cb * 16 + cc) * 72 + cr * 8];
      const bf16x8 kb1 = *(const bf16x8*)&Ks[(cb * 16 + cc) * 72 + 32 + cr * 8];
      f32x4 z = {0.f, 0.f, 0.f, 0.f};
      z = __builtin_amdgcn_mfma_f32_16x16x32_bf16(qf0, kb0, z, 0, 0, 0);
      z = __builtin_amdgcn_mfma_f32_16x16x32_bf16(qf1, kb1, z, 0, 0, 0);
      sc[cb] = z;
    }

    float inv[4];
#pragma unroll
    for (int r = 0; r < 4; ++r) {
      float mx = -1e30f;
#pragma unroll
      for (int cb = 0; cb < 16; ++cb) mx = fmaxf(mx, sc[cb][r]);
      mx = fmaxf(mx, __shfl_xor(mx, 1));
      mx = fmaxf(mx, __shfl_xor(mx, 2));
      mx = fmaxf(mx, __shfl_xor(mx, 4));
      mx = fmaxf(mx, __shfl_xor(mx, 8));
      float sum = 0.f;
#pragma unroll
      for (int cb = 0; cb < 16; ++cb) {
        const float p = __expf((sc[cb][r] - mx) * 0.125f);
        sc[cb][r] = p;
        sum += p;
      }
      sum += __shfl_xor(sum, 1);
      sum += __shfl_xor(sum, 2);
      sum += __shfl_xor(sum, 4);
      sum += __shfl_xor(sum, 8);
      inv[r] = 1.f / sum;
    }

#pragma unroll
    for (int r = 0; r < 4; ++r)
#pragma unroll
      for (int cb = 0; cb < 16; ++cb)
        Pp[(cr * 4 + r) * 264 + cb * 16 + cc] = f2bf(sc[cb][r]);

    bf16x8 pf[8];
#pragma unroll
    for (int ks = 0; ks < 8; ++ks)
      pf[ks] = *(const bf16x8*)&Pp[cc * 264 + ks * 32 + cr * 8];
    f32x4 o[4] = {};
#pragma unroll
    for (int db = 0; db < 4; ++db)
#pragma unroll
      for (int ks = 0; ks < 8; ++ks) {
        const bf16x8 bv = *(const bf16x8*)&Vt[(db * 16 + cc) * 264 + ks * 32 + cr * 8];
        o[db] = __builtin_amdgcn_mfma_f32_16x16x32_bf16(pf[ks], bv, o[db], 0, 0, 0);
      }

#pragma unroll
    for (int db = 0; db < 4; ++db)
#pragma unroll
      for (int r = 0; r < 4; ++r) {
        const int qr = qrow0 + cr * 4 + r;
        x[base + (size_t)qr * 1024 + db * 16 + cc] = f2bf(o[db][r] * inv[r]);
      }
  }
}

// ---- launch ----------------------------------------------------------------

extern "C" void kernel_launch(void* const* d_in, const int* in_sizes, int n_in,
                              void* d_out, int out_size, void* d_ws, size_t ws_size,
                              hipStream_t stream) {
  const float* query = (const float*)d_in[0];
  const float* key_  = (const float*)d_in[1];
  const float* value = (const float*)d_in[2];
  const float* Wq = (const float*)d_in[3];
  const float* bq = (const float*)d_in[4];
  const float* Wk = (const float*)d_in[5];
  const float* bk = (const float*)d_in[6];
  const float* Wv = (const float*)d_in[7];
  const float* bv = (const float*)d_in[8];
  const float* Wo = (const float*)d_in[9];
  const float* bo = (const float*)d_in[10];
  float* out = (float*)d_out;

  // ws: qb/kb/vb bf16 [16384,1024] inputs-as-bf16, qp/kp/vp projections,
  // 4 bf16 weights. 6*33.5 + 8 = ~209 MB... too big; reuse: after projection,
  // the bf16 INPUT copies are dead. Layout: qb,kb,vb | wq..wo | qp,kp,vp.
  const size_t MN = (size_t)16384 * 1024;
  const size_t WN = (size_t)1024 * 1024;
  ushort* qb = (ushort*)d_ws;          // bf16 input copies
  ushort* kb = qb + MN;
  ushort* vb = kb + MN;
  ushort* wqb = vb + MN;
  ushort* wkb = wqb + WN;
  ushort* wvb = wkb + WN;
  ushort* wob = wvb + WN;
  ushort* qp = wob + WN;               // projection outputs
  ushort* kp = qp + MN;
  ushort* vp = kp + MN;

  const dim3 blk(256);
  const dim3 ggrid(128 * 8);  // (M/128) * (N/128) = 1024

  cvt_all<<<dim3(2048), blk, 0, stream>>>(query, key_, value, Wq, Wk, Wv, Wo,
                                          qb, kb, vb, wqb, wkb, wvb, wob);

  gemm_2ph<1><<<ggrid, blk, 0, stream>>>(qb, wqb, bq, qp, 1024, 1024);
  gemm_2ph<1><<<ggrid, blk, 0, stream>>>(kb, wkb, bk, kp, 1024, 1024);
  gemm_2ph<1><<<ggrid, blk, 0, stream>>>(vb, wvb, bv, vp, 1024, 1024);

  attn_kernel<<<dim3(1024), blk, 0, stream>>>(qp, kp, vp, qp /*in-place*/);

  gemm_2ph<0><<<ggrid, blk, 0, stream>>>(qp, wob, bo, out, 1024, 1024);
}